// Round 5
// baseline (2360.853 us; speedup 1.0000x reference)
//
#include <hip/hip_runtime.h>
#include <math.h>

#define DEV __device__ __forceinline__

static constexpr int B_ = 128, T_ = 32, H_ = 512;
static constexpr int S_ = 2048, M_ = 64, OUT_ = 256;
static constexpr int VCS_ = 768;  // vc row stride: 256 (vt) + 453 (ctrl) padded to 768
static constexpr float EPSF = 1e-8f;

DEV float sigmoidf_(float x){ return 1.0f/(1.0f+expf(-x)); }
DEV float softplusf_(float x){ return fmaxf(x,0.0f) + log1pf(expf(-fabsf(x))); }

// ---- packed candidate: (monotonic(value) << 32) | ~idx  => u64 '>' == (value desc, idx asc)
DEV unsigned long long packCand(float v, unsigned idx){
  unsigned u = __float_as_uint(v);
  unsigned m = (u & 0x80000000u) ? ~u : (u | 0x80000000u);
  return ((unsigned long long)m << 32) | (unsigned)(~idx);
}
DEV float unpackVal(unsigned long long e){
  unsigned m = (unsigned)(e >> 32);
  unsigned u = (m & 0x80000000u) ? (m & 0x7FFFFFFFu) : ~m;
  return __uint_as_float(u);
}
DEV unsigned unpackIdx(unsigned long long e){ return ~(unsigned)e; }

DEV void cswp(unsigned long long &a, unsigned long long &b){
  if(a < b){ unsigned long long t=a; a=b; b=t; }   // larger first (descending)
}
// Batcher odd-even mergesort for 8, descending
DEV void sort8(unsigned long long* L){
  cswp(L[0],L[1]); cswp(L[2],L[3]); cswp(L[4],L[5]); cswp(L[6],L[7]);
  cswp(L[0],L[2]); cswp(L[1],L[3]); cswp(L[4],L[6]); cswp(L[5],L[7]);
  cswp(L[1],L[2]); cswp(L[5],L[6]);
  cswp(L[0],L[4]); cswp(L[1],L[5]); cswp(L[2],L[6]); cswp(L[3],L[7]);
  cswp(L[2],L[4]); cswp(L[3],L[5]);
  cswp(L[1],L[2]); cswp(L[3],L[4]); cswp(L[5],L[6]);
}
// bitonic merge of 16, descending (input must be bitonic)
DEV void bmerge16(unsigned long long* C){
  #pragma unroll
  for(int i=0;i<8;i++) cswp(C[i],C[i+8]);
  #pragma unroll
  for(int g=0;g<2;g++){ int o=g*8;
    cswp(C[o+0],C[o+4]); cswp(C[o+1],C[o+5]); cswp(C[o+2],C[o+6]); cswp(C[o+3],C[o+7]); }
  #pragma unroll
  for(int g=0;g<4;g++){ int o=g*4; cswp(C[o+0],C[o+2]); cswp(C[o+1],C[o+3]); }
  #pragma unroll
  for(int g=0;g<8;g++){ int o=g*2; cswp(C[o],C[o+1]); }
}
// butterfly keep-8: each lane holds sorted-8 desc
DEV void butterfly8(unsigned long long* L, int maxMask){
  for(int mask=1; mask<=maxMask; mask<<=1){
    unsigned long long O[8], C[8];
    #pragma unroll
    for(int i=0;i<8;i++) O[i] = __shfl_xor(L[i], mask, 64);
    #pragma unroll
    for(int i=0;i<8;i++){ unsigned long long a=L[i], b=O[7-i]; C[i] = (a>b)?a:b; }
    cswp(C[0],C[4]); cswp(C[1],C[5]); cswp(C[2],C[6]); cswp(C[3],C[7]);
    cswp(C[0],C[2]); cswp(C[1],C[3]); cswp(C[4],C[6]); cswp(C[5],C[7]);
    cswp(C[0],C[1]); cswp(C[2],C[3]); cswp(C[4],C[5]); cswp(C[6],C[7]);
    #pragma unroll
    for(int i=0;i<8;i++) L[i]=C[i];
  }
}
// butterfly keep-16 over all 64 lanes (per-lane lists sorted-16 desc)
DEV void butterfly16(unsigned long long* L){
  for(int mask=1; mask<64; mask<<=1){
    unsigned long long O[16], C[16];
    #pragma unroll
    for(int i=0;i<16;i++) O[i] = __shfl_xor(L[i], mask, 64);
    #pragma unroll
    for(int i=0;i<16;i++){ unsigned long long a=L[i], b=O[15-i]; C[i] = (a>b)?a:b; }
    bmerge16(C);
    #pragma unroll
    for(int i=0;i<16;i++) L[i]=C[i];
  }
}

// ---------------- xg GEMM with virtual gate-permuted B ----------------
// xgp[m, n] = sum_k x[m,k] * W_ih[(n&3)*512 + (n>>2), k] + (b_ih+b_hh)[perm(n)]
// layout: n = 4*j + g  (j = hidden unit, g = gate i,f,g,o)
__global__ __launch_bounds__(256)
void k_xgemm(const float* __restrict__ A,            // x [4096,256]
             const float* __restrict__ Wih,          // [2048,256]
             const float* __restrict__ bih, const float* __restrict__ bhh,
             float* __restrict__ C)                  // xgp [4096,2048]
{
  const int BK=16, LDT=68;
  __shared__ float As[BK*LDT];
  __shared__ float Bs[BK*LDT];
  const int m0 = blockIdx.x*64, n0 = blockIdx.y*64;
  const int tid = threadIdx.x;
  const int tx = tid & 15, ty = tid >> 4;
  float acc[4][4] = {};
  const int row = tid >> 2, kk = (tid & 3) * 4;
  const int nrow = n0 + row;
  const int srcrow = (nrow & 3)*512 + (nrow >> 2);
  for(int k0 = 0; k0 < 256; k0 += BK){
    float4 av = *(const float4*)(A   + (size_t)(m0+row)*256 + k0 + kk);
    float4 bv = *(const float4*)(Wih + (size_t)srcrow*256 + k0 + kk);
    As[(kk+0)*LDT+row]=av.x; As[(kk+1)*LDT+row]=av.y; As[(kk+2)*LDT+row]=av.z; As[(kk+3)*LDT+row]=av.w;
    Bs[(kk+0)*LDT+row]=bv.x; Bs[(kk+1)*LDT+row]=bv.y; Bs[(kk+2)*LDT+row]=bv.z; Bs[(kk+3)*LDT+row]=bv.w;
    __syncthreads();
    #pragma unroll
    for(int k=0;k<BK;k++){
      float4 a = *(const float4*)&As[k*LDT + 4*ty];
      float4 b = *(const float4*)&Bs[k*LDT + 4*tx];
      acc[0][0]+=a.x*b.x; acc[0][1]+=a.x*b.y; acc[0][2]+=a.x*b.z; acc[0][3]+=a.x*b.w;
      acc[1][0]+=a.y*b.x; acc[1][1]+=a.y*b.y; acc[1][2]+=a.y*b.z; acc[1][3]+=a.y*b.w;
      acc[2][0]+=a.z*b.x; acc[2][1]+=a.z*b.y; acc[2][2]+=a.z*b.z; acc[2][3]+=a.z*b.w;
      acc[3][0]+=a.w*b.x; acc[3][1]+=a.w*b.y; acc[3][2]+=a.w*b.z; acc[3][3]+=a.w*b.w;
    }
    __syncthreads();
  }
  const int nb = n0 + 4*tx;
  float bias[4];
  #pragma unroll
  for(int j2=0;j2<4;j2++){
    int n = nb + j2, sr = (n & 3)*512 + (n >> 2);
    bias[j2] = bih[sr] + bhh[sr];
  }
  #pragma unroll
  for(int i=0;i<4;i++){
    float4 o; o.x=acc[i][0]+bias[0]; o.y=acc[i][1]+bias[1];
    o.z=acc[i][2]+bias[2]; o.w=acc[i][3]+bias[3];
    *(float4*)(C + (size_t)(m0+4*ty+i)*2048 + nb) = o;
  }
}

// ---------------- fused gates GEMM + LSTM epilogue ----------------
// gates[b, 4j+g] = h_prev @ W_hh[perm]^T + xgp[b*T+t, 4j+g];  then LSTM cell.
// grid (2,32): m0 = bx*64 (batch), n-tile by*64 covers hidden j in [by*16, by*16+16)
__global__ __launch_bounds__(256)
void k_lstmg(const float* __restrict__ hprev,        // [128,512]
             const float* __restrict__ Whh,          // [2048,512]
             const float* __restrict__ xgp,          // [4096,2048]
             float* __restrict__ c,                  // [128,512]
             float* __restrict__ hout, int t)        // h_all slice [128,512]
{
  const int BK=16, LDT=68;
  __shared__ float As[BK*LDT];
  __shared__ float Bs[BK*LDT];
  const int m0 = blockIdx.x*64, n0 = blockIdx.y*64;
  const int tid = threadIdx.x;
  const int tx = tid & 15, ty = tid >> 4;
  float acc[4][4] = {};
  const int row = tid >> 2, kk = (tid & 3) * 4;
  const int nrow = n0 + row;
  const int srcrow = (nrow & 3)*512 + (nrow >> 2);
  for(int k0 = 0; k0 < 512; k0 += BK){
    float4 av = *(const float4*)(hprev + (size_t)(m0+row)*512 + k0 + kk);
    float4 bv = *(const float4*)(Whh   + (size_t)srcrow*512 + k0 + kk);
    As[(kk+0)*LDT+row]=av.x; As[(kk+1)*LDT+row]=av.y; As[(kk+2)*LDT+row]=av.z; As[(kk+3)*LDT+row]=av.w;
    Bs[(kk+0)*LDT+row]=bv.x; Bs[(kk+1)*LDT+row]=bv.y; Bs[(kk+2)*LDT+row]=bv.z; Bs[(kk+3)*LDT+row]=bv.w;
    __syncthreads();
    #pragma unroll
    for(int k=0;k<BK;k++){
      float4 a = *(const float4*)&As[k*LDT + 4*ty];
      float4 b = *(const float4*)&Bs[k*LDT + 4*tx];
      acc[0][0]+=a.x*b.x; acc[0][1]+=a.x*b.y; acc[0][2]+=a.x*b.z; acc[0][3]+=a.x*b.w;
      acc[1][0]+=a.y*b.x; acc[1][1]+=a.y*b.y; acc[1][2]+=a.y*b.z; acc[1][3]+=a.y*b.w;
      acc[2][0]+=a.z*b.x; acc[2][1]+=a.z*b.y; acc[2][2]+=a.z*b.z; acc[2][3]+=a.z*b.w;
      acc[3][0]+=a.w*b.x; acc[3][1]+=a.w*b.y; acc[3][2]+=a.w*b.z; acc[3][3]+=a.w*b.w;
    }
    __syncthreads();
  }
  // LSTM epilogue: this thread's 4 cols = gates {i,f,g,o} of hidden j
  const int j = (n0 >> 2) + tx;
  #pragma unroll
  for(int i=0;i<4;i++){
    const int b = m0 + 4*ty + i;
    float4 xv = *(const float4*)(xgp + (size_t)(b*T_ + t)*2048 + 4*j);
    float gi = acc[i][0] + xv.x;
    float gf = acc[i][1] + xv.y;
    float gg = acc[i][2] + xv.z;
    float go = acc[i][3] + xv.w;
    float cc = sigmoidf_(gf)*c[b*512 + j] + sigmoidf_(gi)*tanhf(gg);
    float hh = sigmoidf_(go)*tanhf(cc);
    c[b*512 + j] = cc;
    hout[b*512 + j] = hh;
  }
}

// ---------------- vt+ctrl batched GEMM, 64x64 tiles, virtual cat(W_out,W_head,0) ----------------
// vc_all[m, n] (stride 768), m = t*128+b. Rows >=709 of B are zero.
__global__ __launch_bounds__(256)
void k_vtcat(const float* __restrict__ h,            // h_all [4096,512]
             const float* __restrict__ Wout, const float* __restrict__ bout,
             const float* __restrict__ Whead, const float* __restrict__ bhead,
             float* __restrict__ vc)                 // [4096,768]
{
  const int BK=16, LDT=68;
  __shared__ float As[BK*LDT];
  __shared__ float Bs[BK*LDT];
  const int m0 = blockIdx.x*64, n0 = blockIdx.y*64;
  const int tid = threadIdx.x;
  const int tx = tid & 15, ty = tid >> 4;
  float acc[4][4] = {};
  const int row = tid >> 2, kk = (tid & 3) * 4;
  const int nrow = n0 + row;
  const float* Bsrc = (nrow < 256) ? (Wout + (size_t)nrow*512)
                    : (nrow < 709) ? (Whead + (size_t)(nrow-256)*512) : nullptr;
  for(int k0 = 0; k0 < 512; k0 += BK){
    float4 av = *(const float4*)(h + (size_t)(m0+row)*512 + k0 + kk);
    float4 bv = make_float4(0.f,0.f,0.f,0.f);
    if(Bsrc) bv = *(const float4*)(Bsrc + k0 + kk);
    As[(kk+0)*LDT+row]=av.x; As[(kk+1)*LDT+row]=av.y; As[(kk+2)*LDT+row]=av.z; As[(kk+3)*LDT+row]=av.w;
    Bs[(kk+0)*LDT+row]=bv.x; Bs[(kk+1)*LDT+row]=bv.y; Bs[(kk+2)*LDT+row]=bv.z; Bs[(kk+3)*LDT+row]=bv.w;
    __syncthreads();
    #pragma unroll
    for(int k=0;k<BK;k++){
      float4 a = *(const float4*)&As[k*LDT + 4*ty];
      float4 b = *(const float4*)&Bs[k*LDT + 4*tx];
      acc[0][0]+=a.x*b.x; acc[0][1]+=a.x*b.y; acc[0][2]+=a.x*b.z; acc[0][3]+=a.x*b.w;
      acc[1][0]+=a.y*b.x; acc[1][1]+=a.y*b.y; acc[1][2]+=a.y*b.z; acc[1][3]+=a.y*b.w;
      acc[2][0]+=a.z*b.x; acc[2][1]+=a.z*b.y; acc[2][2]+=a.z*b.z; acc[2][3]+=a.z*b.w;
      acc[3][0]+=a.w*b.x; acc[3][1]+=a.w*b.y; acc[3][2]+=a.w*b.z; acc[3][3]+=a.w*b.w;
    }
    __syncthreads();
  }
  const int nb = n0 + 4*tx;
  float bias[4];
  #pragma unroll
  for(int j2=0;j2<4;j2++){
    int n = nb + j2;
    bias[j2] = (n < 256) ? bout[n] : (n < 709) ? bhead[n-256] : 0.f;
  }
  #pragma unroll
  for(int i=0;i<4;i++){
    float4 o; o.x=acc[i][0]+bias[0]; o.y=acc[i][1]+bias[1];
    o.z=acc[i][2]+bias[2]; o.w=acc[i][3]+bias[3];
    *(float4*)(vc + (size_t)(m0+4*ty+i)*VCS_ + nb) = o;
  }
}

// ---------------- phase B: logits + per-chunk stats + per-chunk topk candidates ----------------
__global__ __launch_bounds__(512,4)
void k_scores(const float* __restrict__ memC, const float* __restrict__ vcAll, int t,
              unsigned long long* __restrict__ candW,
              unsigned long long* __restrict__ candR,
              float* __restrict__ statsB)
{
  __shared__ float kk[5*64];
  __shared__ float coef[5];
  __shared__ float tile[5*512];
  const int b = blockIdx.x, ch = blockIdx.y, tid = threadIdx.x;
  const int lane = tid & 63, wid = tid >> 6;
  const float* v = vcAll + ((size_t)t*B_ + b)*VCS_;
  if(tid < 256) kk[tid] = tanhf(v[256+tid]);           // kr (4x64)
  else if(tid < 320) kk[tid] = tanhf(v[516 + tid-256]);// kw (64)
  __syncthreads();
  if(tid < 5){
    float s = 0.f;
    #pragma unroll
    for(int m=0;m<64;m++){ float x = kk[tid*64+m]; s += x*x; }
    float beta = softplusf_( tid<4 ? v[512+tid] : v[580] );
    coef[tid] = beta / fmaxf(sqrtf(s), EPSF);
  }
  __syncthreads();

  // logits for this thread's slot
  {
    const int s = ch*512 + tid;
    const float4* row = (const float4*)(memC + ((size_t)b*S_ + s)*M_);
    float nrm=0.f, d0=0.f, d1=0.f, d2=0.f, d3=0.f, dw=0.f;
    #pragma unroll
    for(int r4=0;r4<16;r4++){
      float4 xa = row[r4];
      float av[4] = {xa.x,xa.y,xa.z,xa.w};
      #pragma unroll
      for(int j=0;j<4;j++){
        const int m = r4*4+j;
        float a = av[j];
        nrm += a*a;
        d0 += a*kk[m];     d1 += a*kk[64+m]; d2 += a*kk[128+m];
        d3 += a*kk[192+m]; dw += a*kk[256+m];
      }
    }
    float inv = 1.0f / fmaxf(sqrtf(nrm), EPSF);
    tile[0*512+tid] = coef[0]*d0*inv;
    tile[1*512+tid] = coef[1]*d1*inv;
    tile[2*512+tid] = coef[2]*d2*inv;
    tile[3*512+tid] = coef[3]*d3*inv;
    tile[4*512+tid] = coef[4]*dw*inv;
  }
  __syncthreads();

  if(wid < 4){
    // read head wid: sorted top-16 of this chunk
    unsigned long long L[16];
    #pragma unroll
    for(int j=0;j<8;j++){
      int i = lane + j*64;
      L[j] = packCand(tile[wid*512 + i], (unsigned)(ch*512 + i));
    }
    sort8(L);
    #pragma unroll
    for(int j=8;j<16;j++) L[j] = 0ULL;
    butterfly16(L);
    if(lane == 0){
      unsigned long long* dst = candR + (((size_t)b*4 + ch)*4 + wid)*16;
      #pragma unroll
      for(int j=0;j<16;j++) dst[j] = L[j];
    }
  } else if(wid == 4){
    // write head: sorted top-8 of this chunk
    unsigned long long L[8];
    #pragma unroll
    for(int j=0;j<8;j++){
      int i = lane + j*64;
      L[j] = packCand(tile[4*512 + i], (unsigned)(ch*512 + i));
    }
    sort8(L);
    butterfly8(L, 32);
    if(lane == 0){
      unsigned long long* dst = candW + ((size_t)b*4 + ch)*8;
      #pragma unroll
      for(int j=0;j<8;j++) dst[j] = L[j];
    }
  } else {
    // stats waves: wid 5 -> heads 0,1; wid 6 -> heads 2,3; wid 7 -> head 4
    int h0 = (wid==5) ? 0 : (wid==6) ? 2 : 4;
    int nh = (wid==7) ? 1 : 2;
    for(int q=0;q<nh;q++){
      int h = h0 + q;
      float x[8];
      #pragma unroll
      for(int j=0;j<8;j++) x[j] = tile[h*512 + lane + j*64];
      float mx = x[0];
      #pragma unroll
      for(int j=1;j<8;j++) mx = fmaxf(mx, x[j]);
      #pragma unroll
      for(int mask=1; mask<64; mask<<=1) mx = fmaxf(mx, __shfl_xor(mx, mask, 64));
      float sm = 0.f;
      #pragma unroll
      for(int j=0;j<8;j++) sm += expf(x[j]-mx);
      #pragma unroll
      for(int mask=1; mask<64; mask<<=1) sm += __shfl_xor(sm, mask, 64);
      if(lane == 0){
        float* st = statsB + (((size_t)b*4 + ch)*5 + h)*2;
        st[0] = mx; st[1] = sm;
      }
    }
  }
}

// ---------------- phase B: write head + mem update + read heads (reads -> global) ----------------
__global__ __launch_bounds__(256)
void k_heads(float* __restrict__ memC,
             const float* __restrict__ vcAll,
             const unsigned long long* __restrict__ candW,
             const unsigned long long* __restrict__ candR,
             const float* __restrict__ statsB,
             float* __restrict__ readsAll, int t)
{
  __shared__ __align__(16) float kr[256];
  __shared__ float er[64], ad[64];
  __shared__ float coefR[4];
  __shared__ __align__(16) float nv[512];
  __shared__ __align__(16) float oldrow[512];
  __shared__ int   widx[8];
  __shared__ float wval[8];

  const int b = blockIdx.x, tid = threadIdx.x;
  const int lane = tid & 63, wave = tid >> 6;
  const float* v = vcAll + ((size_t)t*B_ + b)*VCS_;
  const size_t memb = (size_t)b*(size_t)S_*M_;

  // phase 1: parameter transforms
  kr[tid] = tanhf(v[256+tid]);
  if(tid < 64){ er[tid] = sigmoidf_(v[581+tid]); ad[tid] = tanhf(v[645+tid]); }
  __syncthreads();

  // phase 2: write-head selection (wave 0), coefR (wave 1)
  if(wave == 0){
    float smx[4], ssm[4];
    #pragma unroll
    for(int c=0;c<4;c++){
      const float* st = statsB + (((size_t)b*4 + c)*5 + 4)*2;
      smx[c] = st[0]; ssm[c] = st[1];
    }
    float mxw = fmaxf(fmaxf(smx[0],smx[1]), fmaxf(smx[2],smx[3]));
    float Zw = ssm[0]*expf(smx[0]-mxw) + ssm[1]*expf(smx[1]-mxw)
             + ssm[2]*expf(smx[2]-mxw) + ssm[3]*expf(smx[3]-mxw);
    unsigned long long L[8];
    L[0] = (lane < 32) ? candW[((size_t)b*4 + (lane>>3))*8 + (lane&7)] : 0ULL;
    #pragma unroll
    for(int j=1;j<8;j++) L[j] = 0ULL;
    butterfly8(L, 16);                 // lanes 0-31 contain the data; 5 steps suffice
    if(lane == 0){
      float invZ = 1.0f / Zw;
      #pragma unroll
      for(int p=0;p<8;p++){
        widx[p] = (int)unpackIdx(L[p]);
        wval[p] = expf(unpackVal(L[p]) - mxw) * invZ;
      }
    }
  } else if(wave == 1 && lane < 4){
    float s = 0.f;
    #pragma unroll
    for(int m=0;m<64;m++){ float x = kr[lane*64+m]; s += x*x; }
    coefR[lane] = softplusf_(v[512+lane]) / fmaxf(sqrtf(s), EPSF);
  }
  __syncthreads();

  // phase 3: rank-1 erase/add at the 8 write slots; stash OLD rows for the Z adjustment
  #pragma unroll
  for(int p=0;p<2;p++){
    int idx = tid + p*256;              // 512 = 8 slots x 64 dims
    int j = idx >> 6, m = idx & 63;
    int s = widx[j];
    float w = wval[j];
    size_t ptr = memb + (size_t)s*M_ + m;
    float old = memC[ptr];
    oldrow[j*64+m] = old;
    float x = old * (1.0f - w*er[m]) + w*ad[m];
    memC[ptr] = x;
    nv[j*64+m] = x;
  }
  __syncthreads();

  // phases 4+5 fused, one wave per read head r
  {
    const int r = wave;
    const int sW = lane & 7, g = lane >> 3;
    const float4* nv4 = (const float4*)nv;
    const float4* ov4 = (const float4*)oldrow;
    const float4* kr4 = (const float4*)kr;
    float4 na = nv4[sW*16 + g*2], nb = nv4[sW*16 + g*2 + 1];
    float4 oa = ov4[sW*16 + g*2], ob = ov4[sW*16 + g*2 + 1];
    float4 ka = kr4[r*16  + g*2], kb = kr4[r*16  + g*2 + 1];
    float dot = na.x*ka.x + na.y*ka.y + na.z*ka.z + na.w*ka.w
              + nb.x*kb.x + nb.y*kb.y + nb.z*kb.z + nb.w*kb.w;
    float n2  = na.x*na.x + na.y*na.y + na.z*na.z + na.w*na.w
              + nb.x*nb.x + nb.y*nb.y + nb.z*nb.z + nb.w*nb.w;
    float odot= oa.x*ka.x + oa.y*ka.y + oa.z*ka.z + oa.w*ka.w
              + ob.x*kb.x + ob.y*kb.y + ob.z*kb.z + ob.w*kb.w;
    float on2 = oa.x*oa.x + oa.y*oa.y + oa.z*oa.z + oa.w*oa.w
              + ob.x*ob.x + ob.y*ob.y + ob.z*ob.z + ob.w*ob.w;
    #pragma unroll
    for(int mask=8; mask<64; mask<<=1){
      dot  += __shfl_xor(dot,  mask, 64);
      n2   += __shfl_xor(n2,   mask, 64);
      odot += __shfl_xor(odot, mask, 64);
      on2  += __shfl_xor(on2,  mask, 64);
    }
    float fixv = coefR[r] * dot  / fmaxf(sqrtf(n2),  EPSF);
    float oldv = coefR[r] * odot / fmaxf(sqrtf(on2), EPSF);  // pre-patch read logit @ written slot
    int myw = widx[sW];

    // pre-patch chunk stats for this head
    float scx[4], scs[4];
    #pragma unroll
    for(int c=0;c<4;c++){
      const float* st = statsB + (((size_t)b*4 + c)*5 + r)*2;
      scx[c] = st[0]; scs[c] = st[1];
    }
    float mxp = fmaxf(fmaxf(scx[0],scx[1]), fmaxf(scx[2],scx[3]));

    // candidates: 64 chunk entries (invalidate written) + 8 written entries with new logits
    unsigned long long L[8];
    {
      int c = lane >> 4, rank = lane & 15;
      unsigned long long eA = candR[(((size_t)b*4 + c)*4 + r)*16 + rank];
      unsigned idxA = unpackIdx(eA);
      bool kill = false;
      #pragma unroll
      for(int p=0;p<8;p++) kill = kill || (idxA == (unsigned)widx[p]);
      if(kill) eA = 0ULL;
      unsigned long long eB = (lane < 8) ? packCand(fixv, (unsigned)myw) : 0ULL;
      L[0] = (eA > eB) ? eA : eB;
      L[1] = (eA > eB) ? eB : eA;
      #pragma unroll
      for(int j=2;j<8;j++) L[j] = 0ULL;
    }
    butterfly8(L, 32);                 // all lanes -> global post-patch sorted top-8

    // exact denominator: Z' = Z_pre(mxS) - sum exp(old) + sum exp(new)
    float mxS = fmaxf(mxp, unpackVal(L[0]));
    float Zp = scs[0]*expf(scx[0]-mxS) + scs[1]*expf(scx[1]-mxS)
             + scs[2]*expf(scx[2]-mxS) + scs[3]*expf(scx[3]-mxS);
    float adj = (lane < 8) ? (expf(fixv - mxS) - expf(oldv - mxS)) : 0.f;
    #pragma unroll
    for(int mask=1; mask<64; mask<<=1) adj += __shfl_xor(adj, mask, 64);
    float invZ = 1.0f / (Zp + adj);

    float acc = 0.f;                   // lane == mem dim m
    #pragma unroll
    for(int p=0;p<8;p++){
      float w = expf(unpackVal(L[p]) - mxS) * invZ;
      int si = (int)unpackIdx(L[p]);
      acc += w * memC[memb + (size_t)si*M_ + lane];   // new mem, contiguous row
    }
    readsAll[((size_t)b*T_ + t)*256 + r*64 + lane] = acc;
  }
}

// ---------------- final: out = reads_all @ W_rd^T + b_rd + vt ----------------
// grid (64,4). m = b*T+t; vt row in vc_all is t*128+b (stride 768).
__global__ __launch_bounds__(256)
void k_outg(const float* __restrict__ A,             // reads_all [4096,256]
            const float* __restrict__ Wrd,           // [256,256]
            const float* __restrict__ brd,
            const float* __restrict__ vcAll,
            float* __restrict__ out)
{
  const int BK=16, LDT=68;
  __shared__ float As[BK*LDT];
  __shared__ float Bs[BK*LDT];
  const int m0 = blockIdx.x*64, n0 = blockIdx.y*64;
  const int tid = threadIdx.x;
  const int tx = tid & 15, ty = tid >> 4;
  float acc[4][4] = {};
  const int row = tid >> 2, kk = (tid & 3) * 4;
  for(int k0 = 0; k0 < 256; k0 += BK){
    float4 av = *(const float4*)(A   + (size_t)(m0+row)*256 + k0 + kk);
    float4 bv = *(const float4*)(Wrd + (size_t)(n0+row)*256 + k0 + kk);
    As[(kk+0)*LDT+row]=av.x; As[(kk+1)*LDT+row]=av.y; As[(kk+2)*LDT+row]=av.z; As[(kk+3)*LDT+row]=av.w;
    Bs[(kk+0)*LDT+row]=bv.x; Bs[(kk+1)*LDT+row]=bv.y; Bs[(kk+2)*LDT+row]=bv.z; Bs[(kk+3)*LDT+row]=bv.w;
    __syncthreads();
    #pragma unroll
    for(int k=0;k<BK;k++){
      float4 a = *(const float4*)&As[k*LDT + 4*ty];
      float4 b = *(const float4*)&Bs[k*LDT + 4*tx];
      acc[0][0]+=a.x*b.x; acc[0][1]+=a.x*b.y; acc[0][2]+=a.x*b.z; acc[0][3]+=a.x*b.w;
      acc[1][0]+=a.y*b.x; acc[1][1]+=a.y*b.y; acc[1][2]+=a.y*b.z; acc[1][3]+=a.y*b.w;
      acc[2][0]+=a.z*b.x; acc[2][1]+=a.z*b.y; acc[2][2]+=a.z*b.z; acc[2][3]+=a.z*b.w;
      acc[3][0]+=a.w*b.x; acc[3][1]+=a.w*b.y; acc[3][2]+=a.w*b.z; acc[3][3]+=a.w*b.w;
    }
    __syncthreads();
  }
  const int nb = n0 + 4*tx;
  float4 bb = *(const float4*)(brd + nb);
  #pragma unroll
  for(int i=0;i<4;i++){
    int m = m0 + 4*ty + i;
    int b = m >> 5, tt = m & 31;
    float4 vt = *(const float4*)(vcAll + (size_t)(tt*B_ + b)*VCS_ + nb);
    float4 o;
    o.x = acc[i][0] + bb.x + vt.x;
    o.y = acc[i][1] + bb.y + vt.y;
    o.z = acc[i][2] + bb.z + vt.z;
    o.w = acc[i][3] + bb.w + vt.w;
    *(float4*)(out + (size_t)m*256 + nb) = o;
  }
}

// ---------------- host ----------------
extern "C" void kernel_launch(void* const* d_in, const int* in_sizes, int n_in,
                              void* d_out, int out_size, void* d_ws, size_t ws_size,
                              hipStream_t stream)
{
  const float* x     = (const float*)d_in[0];
  const float* h0    = (const float*)d_in[1];
  const float* c0    = (const float*)d_in[2];
  const float* mem0  = (const float*)d_in[3];
  const float* W_ih  = (const float*)d_in[4];
  const float* W_hh  = (const float*)d_in[5];
  const float* b_ih  = (const float*)d_in[6];
  const float* b_hh  = (const float*)d_in[7];
  const float* W_out = (const float*)d_in[8];
  const float* b_out = (const float*)d_in[9];
  const float* W_rd  = (const float*)d_in[10];
  const float* b_rd  = (const float*)d_in[11];
  const float* W_head= (const float*)d_in[12];
  const float* b_head= (const float*)d_in[13];
  // d_in[14] = K (int) — fixed at 8 by the problem setup; hard-coded in k_heads.
  float* out = (float*)d_out;

  float* ws     = (float*)d_ws;
  float* memC   = ws;                    // 128*2048*64  = 16,777,216  (slot-major [B,S,M])
  float* xgp    = memC   + 16777216;     // 4096*2048    =  8,388,608  (phase A; region reused in B)
  float* h_all  = xgp    + 8388608;      // 32*128*512   =  2,097,152
  float* c      = h_all  + 2097152;      // 128*512      =     65,536
  // phase-B overlays inside the dead xgp region:
  float* vc_all    = xgp;                                  // 4096*768 = 3,145,728
  float* reads_all = xgp + 3145728;                        // 4096*256 = 1,048,576
  unsigned long long* candW  = (unsigned long long*)(xgp + 4194304);  // 128*4*8  u64
  unsigned long long* candR  = candW + 4096;                          // 128*4*4*16 u64
  float*              statsB = (float*)(candR + 32768);               // 128*4*5*2 floats
  const size_t need = (size_t)(27328512) * sizeof(float);
  if(ws_size < need) return;  // ~109 MB workspace required

  hipMemcpyAsync(c, c0, 65536*sizeof(float), hipMemcpyDeviceToDevice, stream);
  hipMemcpyAsync(memC, mem0, (size_t)16777216*sizeof(float), hipMemcpyDeviceToDevice, stream);
  // xgp[b*T+t, 4j+g] = x @ W_ih[perm]^T + (b_ih+b_hh)[perm]
  k_xgemm<<<dim3(64,32),256,0,stream>>>(x, W_ih, b_ih, b_hh, xgp);

  // ---- phase A: fused gates GEMM + LSTM, one launch per step ----
  for(int t=0;t<T_;t++){
    const float* hprev = (t == 0) ? h0 : (h_all + (size_t)(t-1)*65536);
    k_lstmg<<<dim3(2,32),256,0,stream>>>(hprev, W_hh, xgp, c, h_all + (size_t)t*65536, t);
  }
  // ---- all vt+ctrl in one batched 64x64-tile GEMM ----
  k_vtcat<<<dim3(64,12),256,0,stream>>>(h_all, W_out,b_out, W_head,b_head, vc_all);

  // ---- phase B: memory loop ----
  for(int t=0;t<T_;t++){
    k_scores<<<dim3(128,4),512,0,stream>>>(memC, vc_all, t, candW, candR, statsB);
    k_heads<<<128,256,0,stream>>>(memC, vc_all, candW, candR, statsB, reads_all, t);
  }
  // ---- final output GEMM: out = reads_all @ W_rd^T + b_rd + vt ----
  k_outg<<<dim3(64,4),256,0,stream>>>(reads_all, W_rd, b_rd, vc_all, out);
}

// Round 6
// 1886.868 us; speedup vs baseline: 1.2512x; 1.2512x over previous
//
#include <hip/hip_runtime.h>
#include <math.h>

#define DEV __device__ __forceinline__

static constexpr int B_ = 128, T_ = 32, H_ = 512;
static constexpr int S_ = 2048, M_ = 64, OUT_ = 256;
static constexpr int VCS_ = 768;  // vc row stride: 256 (vt) + 453 (ctrl) padded to 768
static constexpr float EPSF = 1e-8f;

DEV float sigmoidf_(float x){ return 1.0f/(1.0f+expf(-x)); }
DEV float softplusf_(float x){ return fmaxf(x,0.0f) + log1pf(expf(-fabsf(x))); }

// ---- packed candidate: (monotonic(value) << 32) | ~idx  => u64 '>' == (value desc, idx asc)
DEV unsigned long long packCand(float v, unsigned idx){
  unsigned u = __float_as_uint(v);
  unsigned m = (u & 0x80000000u) ? ~u : (u | 0x80000000u);
  return ((unsigned long long)m << 32) | (unsigned)(~idx);
}
DEV float unpackVal(unsigned long long e){
  unsigned m = (unsigned)(e >> 32);
  unsigned u = (m & 0x80000000u) ? (m & 0x7FFFFFFFu) : ~m;
  return __uint_as_float(u);
}
DEV unsigned unpackIdx(unsigned long long e){ return ~(unsigned)e; }

DEV void cswp(unsigned long long &a, unsigned long long &b){
  if(a < b){ unsigned long long t=a; a=b; b=t; }   // larger first (descending)
}
// Batcher odd-even mergesort for 8, descending
DEV void sort8(unsigned long long* L){
  cswp(L[0],L[1]); cswp(L[2],L[3]); cswp(L[4],L[5]); cswp(L[6],L[7]);
  cswp(L[0],L[2]); cswp(L[1],L[3]); cswp(L[4],L[6]); cswp(L[5],L[7]);
  cswp(L[1],L[2]); cswp(L[5],L[6]);
  cswp(L[0],L[4]); cswp(L[1],L[5]); cswp(L[2],L[6]); cswp(L[3],L[7]);
  cswp(L[2],L[4]); cswp(L[3],L[5]);
  cswp(L[1],L[2]); cswp(L[3],L[4]); cswp(L[5],L[6]);
}
// bitonic merge of 16, descending (input must be bitonic)
DEV void bmerge16(unsigned long long* C){
  #pragma unroll
  for(int i=0;i<8;i++) cswp(C[i],C[i+8]);
  #pragma unroll
  for(int g=0;g<2;g++){ int o=g*8;
    cswp(C[o+0],C[o+4]); cswp(C[o+1],C[o+5]); cswp(C[o+2],C[o+6]); cswp(C[o+3],C[o+7]); }
  #pragma unroll
  for(int g=0;g<4;g++){ int o=g*4; cswp(C[o+0],C[o+2]); cswp(C[o+1],C[o+3]); }
  #pragma unroll
  for(int g=0;g<8;g++){ int o=g*2; cswp(C[o],C[o+1]); }
}
// butterfly keep-8: each lane holds sorted-8 desc
DEV void butterfly8(unsigned long long* L, int maxMask){
  for(int mask=1; mask<=maxMask; mask<<=1){
    unsigned long long O[8], C[8];
    #pragma unroll
    for(int i=0;i<8;i++) O[i] = __shfl_xor(L[i], mask, 64);
    #pragma unroll
    for(int i=0;i<8;i++){ unsigned long long a=L[i], b=O[7-i]; C[i] = (a>b)?a:b; }
    cswp(C[0],C[4]); cswp(C[1],C[5]); cswp(C[2],C[6]); cswp(C[3],C[7]);
    cswp(C[0],C[2]); cswp(C[1],C[3]); cswp(C[4],C[6]); cswp(C[5],C[7]);
    cswp(C[0],C[1]); cswp(C[2],C[3]); cswp(C[4],C[5]); cswp(C[6],C[7]);
    #pragma unroll
    for(int i=0;i<8;i++) L[i]=C[i];
  }
}
// butterfly keep-16 over all 64 lanes (per-lane lists sorted-16 desc)
DEV void butterfly16(unsigned long long* L){
  for(int mask=1; mask<64; mask<<=1){
    unsigned long long O[16], C[16];
    #pragma unroll
    for(int i=0;i<16;i++) O[i] = __shfl_xor(L[i], mask, 64);
    #pragma unroll
    for(int i=0;i<16;i++){ unsigned long long a=L[i], b=O[15-i]; C[i] = (a>b)?a:b; }
    bmerge16(C);
    #pragma unroll
    for(int i=0;i<16;i++) L[i]=C[i];
  }
}

// ---------------- generic fp32 GEMM  C[M,N] = A[M,K] * Bm[N,K]^T ----------------
__global__ __launch_bounds__(256)
void k_gemm64(const float* __restrict__ A, int lda,
              const float* __restrict__ Bm, int ldb,
              float* __restrict__ C, int ldc,
              int kCount,
              const float* __restrict__ bias0, const float* __restrict__ bias1)
{
  const int BM=64, BN=64, BK=16, LDT=68;
  __shared__ float As[BK*LDT];
  __shared__ float Bs[BK*LDT];
  const int m0 = blockIdx.x*BM, n0 = blockIdx.y*BN;
  const int tid = threadIdx.x;
  const int tx = tid & 15, ty = tid >> 4;
  const int kStart = blockIdx.z * kCount;
  float acc[4][4] = {};
  const int row = tid >> 2, kk = (tid & 3) * 4;
  for(int k0 = kStart; k0 < kStart + kCount; k0 += BK){
    float4 av = *(const float4*)(A  + (size_t)(m0+row)*lda + k0 + kk);
    float4 bv = *(const float4*)(Bm + (size_t)(n0+row)*ldb + k0 + kk);
    As[(kk+0)*LDT+row]=av.x; As[(kk+1)*LDT+row]=av.y; As[(kk+2)*LDT+row]=av.z; As[(kk+3)*LDT+row]=av.w;
    Bs[(kk+0)*LDT+row]=bv.x; Bs[(kk+1)*LDT+row]=bv.y; Bs[(kk+2)*LDT+row]=bv.z; Bs[(kk+3)*LDT+row]=bv.w;
    __syncthreads();
    #pragma unroll
    for(int k=0;k<BK;k++){
      float4 a = *(const float4*)&As[k*LDT + 4*ty];
      float4 b = *(const float4*)&Bs[k*LDT + 4*tx];
      acc[0][0]+=a.x*b.x; acc[0][1]+=a.x*b.y; acc[0][2]+=a.x*b.z; acc[0][3]+=a.x*b.w;
      acc[1][0]+=a.y*b.x; acc[1][1]+=a.y*b.y; acc[1][2]+=a.y*b.z; acc[1][3]+=a.y*b.w;
      acc[2][0]+=a.z*b.x; acc[2][1]+=a.z*b.y; acc[2][2]+=a.z*b.z; acc[2][3]+=a.z*b.w;
      acc[3][0]+=a.w*b.x; acc[3][1]+=a.w*b.y; acc[3][2]+=a.w*b.z; acc[3][3]+=a.w*b.w;
    }
    __syncthreads();
  }
  float* Cz = C + (size_t)blockIdx.z * (size_t)gridDim.x * BM * (size_t)ldc;
  #pragma unroll
  for(int i=0;i<4;i++){
    int m = m0 + 4*ty + i;
    int n = n0 + 4*tx;
    float4 o; o.x=acc[i][0]; o.y=acc[i][1]; o.z=acc[i][2]; o.w=acc[i][3];
    if(bias0){
      o.x += bias0[n]+bias1[n];     o.y += bias0[n+1]+bias1[n+1];
      o.z += bias0[n+2]+bias1[n+2]; o.w += bias0[n+3]+bias1[n+3];
    }
    *(float4*)(Cz + (size_t)m*ldc + n) = o;
  }
}

// ---------------- phase A: LSTM elementwise (writes h into h_all slice) ----------------
__global__ __launch_bounds__(256)
void k_lstm(const float* __restrict__ xg, const float* __restrict__ gp,
            float* __restrict__ hout, float* __restrict__ c, int t)
{
  int idx = blockIdx.x*256 + threadIdx.x;   // 65536 = 128*512
  int b = idx >> 9, j = idx & 511;
  const float* xr = xg + ((size_t)b*T_ + t)*(size_t)(4*H_);
  float gi = xr[j], gf = xr[512+j], gg = xr[1024+j], go = xr[1536+j];
  #pragma unroll
  for(int s4=0;s4<4;s4++){
    const float* pr = gp + ((size_t)s4*B_ + b)*(size_t)(4*H_);
    gi += pr[j]; gf += pr[512+j]; gg += pr[1024+j]; go += pr[1536+j];
  }
  float cc = sigmoidf_(gf)*c[idx] + sigmoidf_(gi)*tanhf(gg);
  float hh = sigmoidf_(go)*tanhf(cc);
  c[idx] = cc; hout[idx] = hh;
}

// ---------------- vt+ctrl batched GEMM, 64x64 tiles, virtual cat(W_out,W_head,0) ----------------
__global__ __launch_bounds__(256)
void k_vtcat(const float* __restrict__ h,            // h_all [4096,512]
             const float* __restrict__ Wout, const float* __restrict__ bout,
             const float* __restrict__ Whead, const float* __restrict__ bhead,
             float* __restrict__ vc)                 // [4096,768]
{
  const int BK=16, LDT=68;
  __shared__ float As[BK*LDT];
  __shared__ float Bs[BK*LDT];
  const int m0 = blockIdx.x*64, n0 = blockIdx.y*64;
  const int tid = threadIdx.x;
  const int tx = tid & 15, ty = tid >> 4;
  float acc[4][4] = {};
  const int row = tid >> 2, kk = (tid & 3) * 4;
  const int nrow = n0 + row;
  const float* Bsrc = (nrow < 256) ? (Wout + (size_t)nrow*512)
                    : (nrow < 709) ? (Whead + (size_t)(nrow-256)*512) : nullptr;
  for(int k0 = 0; k0 < 512; k0 += BK){
    float4 av = *(const float4*)(h + (size_t)(m0+row)*512 + k0 + kk);
    float4 bv = make_float4(0.f,0.f,0.f,0.f);
    if(Bsrc) bv = *(const float4*)(Bsrc + k0 + kk);
    As[(kk+0)*LDT+row]=av.x; As[(kk+1)*LDT+row]=av.y; As[(kk+2)*LDT+row]=av.z; As[(kk+3)*LDT+row]=av.w;
    Bs[(kk+0)*LDT+row]=bv.x; Bs[(kk+1)*LDT+row]=bv.y; Bs[(kk+2)*LDT+row]=bv.z; Bs[(kk+3)*LDT+row]=bv.w;
    __syncthreads();
    #pragma unroll
    for(int k=0;k<BK;k++){
      float4 a = *(const float4*)&As[k*LDT + 4*ty];
      float4 b = *(const float4*)&Bs[k*LDT + 4*tx];
      acc[0][0]+=a.x*b.x; acc[0][1]+=a.x*b.y; acc[0][2]+=a.x*b.z; acc[0][3]+=a.x*b.w;
      acc[1][0]+=a.y*b.x; acc[1][1]+=a.y*b.y; acc[1][2]+=a.y*b.z; acc[1][3]+=a.y*b.w;
      acc[2][0]+=a.z*b.x; acc[2][1]+=a.z*b.y; acc[2][2]+=a.z*b.z; acc[2][3]+=a.z*b.w;
      acc[3][0]+=a.w*b.x; acc[3][1]+=a.w*b.y; acc[3][2]+=a.w*b.z; acc[3][3]+=a.w*b.w;
    }
    __syncthreads();
  }
  const int nb = n0 + 4*tx;
  float bias[4];
  #pragma unroll
  for(int j2=0;j2<4;j2++){
    int n = nb + j2;
    bias[j2] = (n < 256) ? bout[n] : (n < 709) ? bhead[n-256] : 0.f;
  }
  #pragma unroll
  for(int i=0;i<4;i++){
    float4 o; o.x=acc[i][0]+bias[0]; o.y=acc[i][1]+bias[1];
    o.z=acc[i][2]+bias[2]; o.w=acc[i][3]+bias[3];
    *(float4*)(vc + (size_t)(m0+4*ty+i)*VCS_ + nb) = o;
  }
}

// ---------------- phase B: per-chunk dot precompute ----------------
// Every 3 steps: stream memC ONCE, compute raw dots (mem row . tanh(key)) for the
// chunk's nst*5 keys + row norms; clear written-flags. L0 layout [b][st][h][2048] (slot-minor).
__global__ __launch_bounds__(256)
void k_dots(const float* __restrict__ memC, const float* __restrict__ vcAll,
            int t0, int nst,
            float* __restrict__ L0, float* __restrict__ normC,
            unsigned char* __restrict__ flags)
{
  __shared__ float kkd[960];           // up to 3 steps x 5 heads x 64
  const int b = blockIdx.x, g = blockIdx.y, tid = threadIdx.x;
  const int s = g*256 + tid;
  flags[(size_t)b*S_ + s] = 0;
  const int tot = 320*nst;
  for(int q = tid; q < tot; q += 256){
    int st = q/320, rem = q - st*320;
    int h = rem >> 6, m = rem & 63;
    const float* v = vcAll + ((size_t)(t0+st)*B_ + b)*VCS_;
    kkd[q] = tanhf( (h<4) ? v[256 + h*64 + m] : v[516 + m] );
  }
  __syncthreads();
  const float4* row = (const float4*)(memC + ((size_t)b*S_ + s)*M_);
  float acc[15];
  #pragma unroll
  for(int i=0;i<15;i++) acc[i]=0.f;
  float nrm = 0.f;
  #pragma unroll
  for(int r4=0;r4<16;r4++){
    float4 xa = row[r4];
    nrm += xa.x*xa.x; nrm += xa.y*xa.y; nrm += xa.z*xa.z; nrm += xa.w*xa.w;
    #pragma unroll
    for(int st=0;st<3;st++){
      if(st < nst){
        #pragma unroll
        for(int h=0;h<5;h++){
          const float* kp = &kkd[st*320 + h*64 + 4*r4];
          float a = acc[st*5+h];
          a += xa.x*kp[0]; a += xa.y*kp[1]; a += xa.z*kp[2]; a += xa.w*kp[3];
          acc[st*5+h] = a;
        }
      }
    }
  }
  normC[(size_t)b*S_ + s] = nrm;
  for(int st=0; st<nst; st++){
    #pragma unroll
    for(int h=0;h<5;h++)
      L0[(((size_t)b*3 + st)*5 + h)*S_ + s] = acc[st*5+h];
  }
}

// ---------------- phase B: logits (from L0 or fresh for written rows) + stats + topk ----------------
__global__ __launch_bounds__(512,4)
void k_scores2(const float* __restrict__ memC, const float* __restrict__ vcAll,
               int t, int tch,
               const float* __restrict__ L0, const float* __restrict__ normC,
               const unsigned char* __restrict__ flags,
               unsigned long long* __restrict__ candW,
               unsigned long long* __restrict__ candR,
               float* __restrict__ statsB)
{
  __shared__ float kk[5*64];
  __shared__ float coef[5];
  __shared__ float tile[5*512];
  const int b = blockIdx.x, ch = blockIdx.y, tid = threadIdx.x;
  const int lane = tid & 63, wid = tid >> 6;
  const float* v = vcAll + ((size_t)t*B_ + b)*VCS_;
  if(tid < 256) kk[tid] = tanhf(v[256+tid]);           // kr (4x64)
  else if(tid < 320) kk[tid] = tanhf(v[516 + tid-256]);// kw (64)
  __syncthreads();
  if(tid < 5){
    float s = 0.f;
    #pragma unroll
    for(int m=0;m<64;m++){ float x = kk[tid*64+m]; s += x*x; }
    float beta = softplusf_( tid<4 ? v[512+tid] : v[580] );
    coef[tid] = beta / fmaxf(sqrtf(s), EPSF);
  }
  __syncthreads();

  // logits for this thread's slot
  {
    const int s = ch*512 + tid;
    float nrm, d0, d1, d2, d3, dw;
    if(flags[(size_t)b*S_ + s]){
      // row written since chunk start: fresh recompute (identical to the old path)
      const float4* row = (const float4*)(memC + ((size_t)b*S_ + s)*M_);
      nrm=0.f; d0=0.f; d1=0.f; d2=0.f; d3=0.f; dw=0.f;
      #pragma unroll
      for(int r4=0;r4<16;r4++){
        float4 xa = row[r4];
        float av[4] = {xa.x,xa.y,xa.z,xa.w};
        #pragma unroll
        for(int j=0;j<4;j++){
          const int m = r4*4+j;
          float a = av[j];
          nrm += a*a;
          d0 += a*kk[m];     d1 += a*kk[64+m]; d2 += a*kk[128+m];
          d3 += a*kk[192+m]; dw += a*kk[256+m];
        }
      }
    } else {
      nrm = normC[(size_t)b*S_ + s];
      const float* Lb = L0 + (((size_t)b*3 + tch)*5)*(size_t)S_ + s;
      d0 = Lb[0];      d1 = Lb[S_];     d2 = Lb[2*S_];
      d3 = Lb[3*(size_t)S_]; dw = Lb[4*(size_t)S_];
    }
    float inv = 1.0f / fmaxf(sqrtf(nrm), EPSF);
    tile[0*512+tid] = coef[0]*d0*inv;
    tile[1*512+tid] = coef[1]*d1*inv;
    tile[2*512+tid] = coef[2]*d2*inv;
    tile[3*512+tid] = coef[3]*d3*inv;
    tile[4*512+tid] = coef[4]*dw*inv;
  }
  __syncthreads();

  if(wid < 4){
    // read head wid: sorted top-16 of this chunk
    unsigned long long L[16];
    #pragma unroll
    for(int j=0;j<8;j++){
      int i = lane + j*64;
      L[j] = packCand(tile[wid*512 + i], (unsigned)(ch*512 + i));
    }
    sort8(L);
    #pragma unroll
    for(int j=8;j<16;j++) L[j] = 0ULL;
    butterfly16(L);
    if(lane == 0){
      unsigned long long* dst = candR + (((size_t)b*4 + ch)*4 + wid)*16;
      #pragma unroll
      for(int j=0;j<16;j++) dst[j] = L[j];
    }
  } else if(wid == 4){
    // write head: sorted top-8 of this chunk
    unsigned long long L[8];
    #pragma unroll
    for(int j=0;j<8;j++){
      int i = lane + j*64;
      L[j] = packCand(tile[4*512 + i], (unsigned)(ch*512 + i));
    }
    sort8(L);
    butterfly8(L, 32);
    if(lane == 0){
      unsigned long long* dst = candW + ((size_t)b*4 + ch)*8;
      #pragma unroll
      for(int j=0;j<8;j++) dst[j] = L[j];
    }
  } else {
    // stats waves: wid 5 -> heads 0,1; wid 6 -> heads 2,3; wid 7 -> head 4
    int h0 = (wid==5) ? 0 : (wid==6) ? 2 : 4;
    int nh = (wid==7) ? 1 : 2;
    for(int q=0;q<nh;q++){
      int h = h0 + q;
      float x[8];
      #pragma unroll
      for(int j=0;j<8;j++) x[j] = tile[h*512 + lane + j*64];
      float mx = x[0];
      #pragma unroll
      for(int j=1;j<8;j++) mx = fmaxf(mx, x[j]);
      #pragma unroll
      for(int mask=1; mask<64; mask<<=1) mx = fmaxf(mx, __shfl_xor(mx, mask, 64));
      float sm = 0.f;
      #pragma unroll
      for(int j=0;j<8;j++) sm += expf(x[j]-mx);
      #pragma unroll
      for(int mask=1; mask<64; mask<<=1) sm += __shfl_xor(sm, mask, 64);
      if(lane == 0){
        float* st = statsB + (((size_t)b*4 + ch)*5 + h)*2;
        st[0] = mx; st[1] = sm;
      }
    }
  }
}

// ---------------- phase B: write head + mem update + read heads (reads -> global) ----------------
__global__ __launch_bounds__(256)
void k_heads(float* __restrict__ memC,
             const float* __restrict__ vcAll,
             const unsigned long long* __restrict__ candW,
             const unsigned long long* __restrict__ candR,
             const float* __restrict__ statsB,
             unsigned char* __restrict__ flags,
             float* __restrict__ readsAll, int t)
{
  __shared__ __align__(16) float kr[256];
  __shared__ float er[64], ad[64];
  __shared__ float coefR[4];
  __shared__ __align__(16) float nv[512];
  __shared__ __align__(16) float oldrow[512];
  __shared__ int   widx[8];
  __shared__ float wval[8];

  const int b = blockIdx.x, tid = threadIdx.x;
  const int lane = tid & 63, wave = tid >> 6;
  const float* v = vcAll + ((size_t)t*B_ + b)*VCS_;
  const size_t memb = (size_t)b*(size_t)S_*M_;

  // phase 1: parameter transforms
  kr[tid] = tanhf(v[256+tid]);
  if(tid < 64){ er[tid] = sigmoidf_(v[581+tid]); ad[tid] = tanhf(v[645+tid]); }
  __syncthreads();

  // phase 2: write-head selection (wave 0), coefR (wave 1)
  if(wave == 0){
    float smx[4], ssm[4];
    #pragma unroll
    for(int c=0;c<4;c++){
      const float* st = statsB + (((size_t)b*4 + c)*5 + 4)*2;
      smx[c] = st[0]; ssm[c] = st[1];
    }
    float mxw = fmaxf(fmaxf(smx[0],smx[1]), fmaxf(smx[2],smx[3]));
    float Zw = ssm[0]*expf(smx[0]-mxw) + ssm[1]*expf(smx[1]-mxw)
             + ssm[2]*expf(smx[2]-mxw) + ssm[3]*expf(smx[3]-mxw);
    unsigned long long L[8];
    L[0] = (lane < 32) ? candW[((size_t)b*4 + (lane>>3))*8 + (lane&7)] : 0ULL;
    #pragma unroll
    for(int j=1;j<8;j++) L[j] = 0ULL;
    butterfly8(L, 16);                 // lanes 0-31 contain the data; 5 steps suffice
    if(lane == 0){
      float invZ = 1.0f / Zw;
      #pragma unroll
      for(int p=0;p<8;p++){
        widx[p] = (int)unpackIdx(L[p]);
        wval[p] = expf(unpackVal(L[p]) - mxw) * invZ;
      }
    }
  } else if(wave == 1 && lane < 4){
    float s = 0.f;
    #pragma unroll
    for(int m=0;m<64;m++){ float x = kr[lane*64+m]; s += x*x; }
    coefR[lane] = softplusf_(v[512+lane]) / fmaxf(sqrtf(s), EPSF);
  }
  __syncthreads();

  // mark written slots for the chunk-delta logits scheme
  if(tid < 8) flags[(size_t)b*S_ + widx[tid]] = 1;

  // phase 3: rank-1 erase/add at the 8 write slots; stash OLD rows for the Z adjustment
  #pragma unroll
  for(int p=0;p<2;p++){
    int idx = tid + p*256;              // 512 = 8 slots x 64 dims
    int j = idx >> 6, m = idx & 63;
    int s = widx[j];
    float w = wval[j];
    size_t ptr = memb + (size_t)s*M_ + m;
    float old = memC[ptr];
    oldrow[j*64+m] = old;
    float x = old * (1.0f - w*er[m]) + w*ad[m];
    memC[ptr] = x;
    nv[j*64+m] = x;
  }
  __syncthreads();

  // phases 4+5 fused, one wave per read head r
  {
    const int r = wave;
    const int sW = lane & 7, g = lane >> 3;
    const float4* nv4 = (const float4*)nv;
    const float4* ov4 = (const float4*)oldrow;
    const float4* kr4 = (const float4*)kr;
    float4 na = nv4[sW*16 + g*2], nb = nv4[sW*16 + g*2 + 1];
    float4 oa = ov4[sW*16 + g*2], ob = ov4[sW*16 + g*2 + 1];
    float4 ka = kr4[r*16  + g*2], kb = kr4[r*16  + g*2 + 1];
    float dot = na.x*ka.x + na.y*ka.y + na.z*ka.z + na.w*ka.w
              + nb.x*kb.x + nb.y*kb.y + nb.z*kb.z + nb.w*kb.w;
    float n2  = na.x*na.x + na.y*na.y + na.z*na.z + na.w*na.w
              + nb.x*nb.x + nb.y*nb.y + nb.z*nb.z + nb.w*nb.w;
    float odot= oa.x*ka.x + oa.y*ka.y + oa.z*ka.z + oa.w*ka.w
              + ob.x*kb.x + ob.y*kb.y + ob.z*kb.z + ob.w*kb.w;
    float on2 = oa.x*oa.x + oa.y*oa.y + oa.z*oa.z + oa.w*oa.w
              + ob.x*ob.x + ob.y*ob.y + ob.z*ob.z + ob.w*ob.w;
    #pragma unroll
    for(int mask=8; mask<64; mask<<=1){
      dot  += __shfl_xor(dot,  mask, 64);
      n2   += __shfl_xor(n2,   mask, 64);
      odot += __shfl_xor(odot, mask, 64);
      on2  += __shfl_xor(on2,  mask, 64);
    }
    float fixv = coefR[r] * dot  / fmaxf(sqrtf(n2),  EPSF);
    float oldv = coefR[r] * odot / fmaxf(sqrtf(on2), EPSF);  // pre-patch read logit @ written slot
    int myw = widx[sW];

    // pre-patch chunk stats for this head
    float scx[4], scs[4];
    #pragma unroll
    for(int c=0;c<4;c++){
      const float* st = statsB + (((size_t)b*4 + c)*5 + r)*2;
      scx[c] = st[0]; scs[c] = st[1];
    }
    float mxp = fmaxf(fmaxf(scx[0],scx[1]), fmaxf(scx[2],scx[3]));

    // candidates: 64 chunk entries (invalidate written) + 8 written entries with new logits
    unsigned long long L[8];
    {
      int c = lane >> 4, rank = lane & 15;
      unsigned long long eA = candR[(((size_t)b*4 + c)*4 + r)*16 + rank];
      unsigned idxA = unpackIdx(eA);
      bool kill = false;
      #pragma unroll
      for(int p=0;p<8;p++) kill = kill || (idxA == (unsigned)widx[p]);
      if(kill) eA = 0ULL;
      unsigned long long eB = (lane < 8) ? packCand(fixv, (unsigned)myw) : 0ULL;
      L[0] = (eA > eB) ? eA : eB;
      L[1] = (eA > eB) ? eB : eA;
      #pragma unroll
      for(int j=2;j<8;j++) L[j] = 0ULL;
    }
    butterfly8(L, 32);                 // all lanes -> global post-patch sorted top-8

    // exact denominator: Z' = Z_pre(mxS) - sum exp(old) + sum exp(new)
    float mxS = fmaxf(mxp, unpackVal(L[0]));
    float Zp = scs[0]*expf(scx[0]-mxS) + scs[1]*expf(scx[1]-mxS)
             + scs[2]*expf(scx[2]-mxS) + scs[3]*expf(scx[3]-mxS);
    float adj = (lane < 8) ? (expf(fixv - mxS) - expf(oldv - mxS)) : 0.f;
    #pragma unroll
    for(int mask=1; mask<64; mask<<=1) adj += __shfl_xor(adj, mask, 64);
    float invZ = 1.0f / (Zp + adj);

    float acc = 0.f;                   // lane == mem dim m
    #pragma unroll
    for(int p=0;p<8;p++){
      float w = expf(unpackVal(L[p]) - mxS) * invZ;
      int si = (int)unpackIdx(L[p]);
      acc += w * memC[memb + (size_t)si*M_ + lane];   // new mem, contiguous row
    }
    readsAll[((size_t)b*T_ + t)*256 + r*64 + lane] = acc;
  }
}

// ---------------- final: out = reads_all @ W_rd^T + b_rd + vt ----------------
__global__ __launch_bounds__(256)
void k_outg(const float* __restrict__ A,             // reads_all [4096,256]
            const float* __restrict__ Wrd,           // [256,256]
            const float* __restrict__ brd,
            const float* __restrict__ vcAll,
            float* __restrict__ out)
{
  const int BK=16, LDT=68;
  __shared__ float As[BK*LDT];
  __shared__ float Bs[BK*LDT];
  const int m0 = blockIdx.x*64, n0 = blockIdx.y*64;
  const int tid = threadIdx.x;
  const int tx = tid & 15, ty = tid >> 4;
  float acc[4][4] = {};
  const int row = tid >> 2, kk = (tid & 3) * 4;
  for(int k0 = 0; k0 < 256; k0 += BK){
    float4 av = *(const float4*)(A   + (size_t)(m0+row)*256 + k0 + kk);
    float4 bv = *(const float4*)(Wrd + (size_t)(n0+row)*256 + k0 + kk);
    As[(kk+0)*LDT+row]=av.x; As[(kk+1)*LDT+row]=av.y; As[(kk+2)*LDT+row]=av.z; As[(kk+3)*LDT+row]=av.w;
    Bs[(kk+0)*LDT+row]=bv.x; Bs[(kk+1)*LDT+row]=bv.y; Bs[(kk+2)*LDT+row]=bv.z; Bs[(kk+3)*LDT+row]=bv.w;
    __syncthreads();
    #pragma unroll
    for(int k=0;k<BK;k++){
      float4 a = *(const float4*)&As[k*LDT + 4*ty];
      float4 b = *(const float4*)&Bs[k*LDT + 4*tx];
      acc[0][0]+=a.x*b.x; acc[0][1]+=a.x*b.y; acc[0][2]+=a.x*b.z; acc[0][3]+=a.x*b.w;
      acc[1][0]+=a.y*b.x; acc[1][1]+=a.y*b.y; acc[1][2]+=a.y*b.z; acc[1][3]+=a.y*b.w;
      acc[2][0]+=a.z*b.x; acc[2][1]+=a.z*b.y; acc[2][2]+=a.z*b.z; acc[2][3]+=a.z*b.w;
      acc[3][0]+=a.w*b.x; acc[3][1]+=a.w*b.y; acc[3][2]+=a.w*b.z; acc[3][3]+=a.w*b.w;
    }
    __syncthreads();
  }
  const int nb = n0 + 4*tx;
  float4 bb = *(const float4*)(brd + nb);
  #pragma unroll
  for(int i=0;i<4;i++){
    int m = m0 + 4*ty + i;
    int b = m >> 5, tt = m & 31;
    float4 vt = *(const float4*)(vcAll + (size_t)(tt*B_ + b)*VCS_ + nb);
    float4 o;
    o.x = acc[i][0] + bb.x + vt.x;
    o.y = acc[i][1] + bb.y + vt.y;
    o.z = acc[i][2] + bb.z + vt.z;
    o.w = acc[i][3] + bb.w + vt.w;
    *(float4*)(out + (size_t)m*256 + nb) = o;
  }
}

// ---------------- host ----------------
extern "C" void kernel_launch(void* const* d_in, const int* in_sizes, int n_in,
                              void* d_out, int out_size, void* d_ws, size_t ws_size,
                              hipStream_t stream)
{
  const float* x     = (const float*)d_in[0];
  const float* h0    = (const float*)d_in[1];
  const float* c0    = (const float*)d_in[2];
  const float* mem0  = (const float*)d_in[3];
  const float* W_ih  = (const float*)d_in[4];
  const float* W_hh  = (const float*)d_in[5];
  const float* b_ih  = (const float*)d_in[6];
  const float* b_hh  = (const float*)d_in[7];
  const float* W_out = (const float*)d_in[8];
  const float* b_out = (const float*)d_in[9];
  const float* W_rd  = (const float*)d_in[10];
  const float* b_rd  = (const float*)d_in[11];
  const float* W_head= (const float*)d_in[12];
  const float* b_head= (const float*)d_in[13];
  // d_in[14] = K (int) — fixed at 8 by the problem setup; hard-coded in k_heads.
  float* out = (float*)d_out;

  float* ws     = (float*)d_ws;
  float* memC   = ws;                    // 128*2048*64  = 16,777,216  (slot-major [B,S,M])
  float* xg     = memC   + 16777216;     // 4096*2048    =  8,388,608  (phase A; region reused in B)
  float* h_all  = xg     + 8388608;      // 32*128*512   =  2,097,152
  float* c      = h_all  + 2097152;      // 128*512      =     65,536
  float* gparts = c      + 65536;        // 4*128*2048   =  1,048,576  (phase A; = reads_all in B)
  float* reads_all = gparts;             // 4096*256     =  1,048,576  (phase B)
  // phase-B overlays inside the dead xg region (8,388,608 floats):
  float* vc_all = xg;                                                 // 4096*768 = 3,145,728
  unsigned long long* candW  = (unsigned long long*)(xg + 3145728);   // 4096 u64    (8,192 f)
  unsigned long long* candR  = candW + 4096;                          // 32768 u64  (65,536 f)
  float*              statsB = (float*)(candR + 32768);               // 5,120 f
  unsigned char*      flags  = (unsigned char*)(statsB + 5120);       // 128*2048 u8 (65,536 f)
  float*              normC  = statsB + 5120 + 65536;                 // 262,144 f
  float*              L0     = normC + 262144;                        // 128*3*5*2048 = 3,932,160 f
  // in-xg total: 7,484,416 <= 8,388,608  ✓
  const size_t need = (size_t)(28377088) * sizeof(float);
  if(ws_size < need) return;  // ~113.5 MB workspace (<= round-4 proven capacity)

  hipMemcpyAsync(c, c0, 65536*sizeof(float), hipMemcpyDeviceToDevice, stream);
  hipMemcpyAsync(memC, mem0, (size_t)16777216*sizeof(float), hipMemcpyDeviceToDevice, stream);
  // xg[b*T+t, :] = x @ W_ih^T + (b_ih+b_hh)
  k_gemm64<<<dim3(64,32,1),256,0,stream>>>(x,256, W_ih,256, xg,2048, 256, b_ih,b_hh);

  // ---- phase A: LSTM recurrence (independent of memory) -> h_all ----
  for(int t=0;t<T_;t++){
    const float* hprev = (t == 0) ? h0 : (h_all + (size_t)(t-1)*65536);
    k_gemm64<<<dim3(2,32,4),256,0,stream>>>(hprev,512, W_hh,512, gparts,2048, 128, nullptr,nullptr);
    k_lstm<<<256,256,0,stream>>>(xg, gparts, h_all + (size_t)t*65536, c, t);
  }
  // ---- all vt+ctrl in one batched 64x64-tile GEMM ----
  k_vtcat<<<dim3(64,12),256,0,stream>>>(h_all, W_out,b_out, W_head,b_head, vc_all);

  // ---- phase B: memory loop with 3-step dot precompute chunks ----
  for(int t=0;t<T_;t++){
    if((t % 3) == 0){
      int nst = (T_ - t < 3) ? (T_ - t) : 3;
      k_dots<<<dim3(128,8),256,0,stream>>>(memC, vc_all, t, nst, L0, normC, flags);
    }
    k_scores2<<<dim3(128,4),512,0,stream>>>(memC, vc_all, t, t % 3, L0, normC, flags,
                                            candW, candR, statsB);
    k_heads<<<128,256,0,stream>>>(memC, vc_all, candW, candR, statsB, flags, reads_all, t);
  }
  // ---- final output GEMM: out = reads_all @ W_rd^T + b_rd + vt ----
  k_outg<<<dim3(64,4),256,0,stream>>>(reads_all, W_rd, b_rd, vc_all, out);
}